// Round 2
// baseline (571.410 us; speedup 1.0000x reference)
//
#include <hip/hip_runtime.h>

typedef unsigned short ushort_t;
typedef __attribute__((ext_vector_type(8))) short bf16x8;
typedef __attribute__((ext_vector_type(4))) float f32x4;

#define NPOS 16384   // H*W
#define CIN 128
#define O3  384
#define HID 128

__device__ inline float b2f(ushort_t u) {
    union { unsigned int i; float f; } z; z.i = ((unsigned int)u) << 16; return z.f;
}
__device__ inline ushort_t f2b(float f) {
    union { float f; unsigned int u; } x; x.f = f;
    unsigned int lsb = (x.u >> 16) & 1u;
    unsigned int r = x.u + 0x7fffu + lsb;
    return (ushort_t)(r >> 16);
}

// Load 8 consecutive fp32, round to bf16 fragment.
__device__ inline bf16x8 load8_f32(const float* __restrict__ p) {
    float4 a = *(const float4*)p;
    float4 b = *(const float4*)(p + 4);
    bf16x8 r;
    r[0] = (short)f2b(a.x); r[1] = (short)f2b(a.y); r[2] = (short)f2b(a.z); r[3] = (short)f2b(a.w);
    r[4] = (short)f2b(b.x); r[5] = (short)f2b(b.y); r[6] = (short)f2b(b.z); r[7] = (short)f2b(b.w);
    return r;
}

// ---------------- Kernel 0: one-time fp32 -> bf16 weight conversion ----------------
__global__ __launch_bounds__(256) void k_cvt(const float* __restrict__ wq,
                                             const float* __restrict__ wo,
                                             ushort_t* __restrict__ wq_bf,
                                             ushort_t* __restrict__ wo_bf) {
    int i = blockIdx.x * 256 + threadIdx.x;   // 0 .. 65535
    if (i < O3 * CIN) wq_bf[i] = f2b(wq[i]);
    else              wo_bf[i - O3 * CIN] = f2b(wo[i - O3 * CIN]);
}

// Stage a (128 chan x 32 pos) fp32 tile, src row-stride NPOS, bf16-transposed into
// lds[pos 32][chan 136] (136*2B = 272B row, 16B aligned -> clean ds_read_b128).
__device__ inline void stage_tile_f32(const float* __restrict__ src, int t, ushort_t (*xt)[136]) {
    int c0 = t >> 3;           // 0..31
    int nq = (t & 7) * 4;      // 0..28
#pragma unroll
    for (int it = 0; it < 4; ++it) {
        int c = it * 32 + c0;
        float4 v = *(const float4*)(src + (size_t)c * NPOS + nq);
        xt[nq + 0][c] = f2b(v.x);
        xt[nq + 1][c] = f2b(v.y);
        xt[nq + 2][c] = f2b(v.z);
        xt[nq + 3][c] = f2b(v.w);
    }
}

// Stage a (128 x 32) bf16 tile (for attn in k_out), same LDS layout.
__device__ inline void stage_tile_bf(const ushort_t* __restrict__ src, int t, ushort_t (*xt)[136]) {
    int c0 = t >> 3;
    int nq = (t & 7) * 4;
#pragma unroll
    for (int it = 0; it < 4; ++it) {
        int c = it * 32 + c0;
        ushort4 v = *(const ushort4*)(src + (size_t)c * NPOS + nq);
        xt[nq + 0][c] = v.x;
        xt[nq + 1][c] = v.y;
        xt[nq + 2][c] = v.z;
        xt[nq + 3][c] = v.w;
    }
}

// ---------------- Kernel 1: qkv(bf16 ws) = w_qkv(384x128) @ x_b(128x16384) ----------------
__global__ __launch_bounds__(256) void k_qkv(const float* __restrict__ x,
                                             const ushort_t* __restrict__ wq,
                                             ushort_t* __restrict__ qkv) {
    __shared__ ushort_t xt[32][136];
    int t = threadIdx.x;
    int b = blockIdx.y;
    int p0 = blockIdx.x * 32;
    stage_tile_f32(x + (size_t)b * CIN * NPOS + p0, t, xt);
    __syncthreads();

    int w = t >> 6, l = t & 63, lr = l & 15, lq = l >> 4;
    f32x4 acc[6][2];
#pragma unroll
    for (int i = 0; i < 6; ++i)
#pragma unroll
        for (int nt = 0; nt < 2; ++nt) acc[i][nt] = (f32x4){0.f, 0.f, 0.f, 0.f};

#pragma unroll
    for (int kk = 0; kk < 4; ++kk) {
        bf16x8 a[6], bb[2];
#pragma unroll
        for (int i = 0; i < 6; ++i)
            a[i] = *(const bf16x8*)(wq + (size_t)((w * 6 + i) * 16 + lr) * CIN + kk * 32 + lq * 8);
#pragma unroll
        for (int nt = 0; nt < 2; ++nt)
            bb[nt] = *(const bf16x8*)(&xt[nt * 16 + lr][kk * 32 + lq * 8]);
#pragma unroll
        for (int i = 0; i < 6; ++i)
#pragma unroll
            for (int nt = 0; nt < 2; ++nt)
                acc[i][nt] = __builtin_amdgcn_mfma_f32_16x16x32_bf16(a[i], bb[nt], acc[i][nt], 0, 0, 0);
    }

#pragma unroll
    for (int i = 0; i < 6; ++i) {
        int o = w * 96 + i * 16 + lq * 4;
#pragma unroll
        for (int nt = 0; nt < 2; ++nt) {
            int p = p0 + nt * 16 + lr;
#pragma unroll
            for (int r = 0; r < 4; ++r)
                qkv[((size_t)b * O3 + o + r) * NPOS + p] = f2b(acc[i][nt][r]);
        }
    }
}

// ---------------- Kernel 2: per-(b,h,d) k-row max & 1/sumexp over n ----------------
__global__ __launch_bounds__(256) void k_stats(const ushort_t* __restrict__ qkv,
                                               float* __restrict__ kmax,
                                               float* __restrict__ kinv) {
    int r = blockIdx.x;          // 0..2047
    int b = r >> 7, loc = r & 127;
    const ushort_t* row = qkv + ((size_t)b * O3 + 128 + loc) * NPOS;
    int t = threadIdx.x;
    __shared__ float red[256];

    float m = -1e30f;
    for (int i = t; i < NPOS; i += 256) m = fmaxf(m, b2f(row[i]));
    red[t] = m; __syncthreads();
    for (int s = 128; s > 0; s >>= 1) { if (t < s) red[t] = fmaxf(red[t], red[t + s]); __syncthreads(); }
    m = red[0]; __syncthreads();

    float sum = 0.f;
    for (int i = t; i < NPOS; i += 256) sum += __expf(b2f(row[i]) - m);
    red[t] = sum; __syncthreads();
    for (int s = 128; s > 0; s >>= 1) { if (t < s) red[t] += red[t + s]; __syncthreads(); }
    if (t == 0) { kmax[r] = m; kinv[r] = 1.0f / red[0]; }
}

// ---------------- Kernel 3: ctx_raw[bh][d][e] = sum_n exp(k[d,n]-max_d)*v[e,n] ----------------
__global__ __launch_bounds__(64) void k_ctx(const ushort_t* __restrict__ qkv,
                                            const float* __restrict__ kmax,
                                            float* __restrict__ ctx) {
    int bh = blockIdx.y, b = bh >> 2, h = bh & 3;
    int n0 = blockIdx.x * 512;
    int l = threadIdx.x, lr = l & 15, lq = l >> 4;
    const ushort_t* kb = qkv + ((size_t)b * O3 + 128 + h * 32) * NPOS;
    const ushort_t* vb = qkv + ((size_t)b * O3 + 256 + h * 32) * NPOS;
    float km[2];
    km[0] = kmax[bh * 32 + lr];
    km[1] = kmax[bh * 32 + 16 + lr];

    f32x4 acc[2][2];
#pragma unroll
    for (int mt = 0; mt < 2; ++mt)
#pragma unroll
        for (int nt = 0; nt < 2; ++nt) acc[mt][nt] = (f32x4){0.f, 0.f, 0.f, 0.f};

    for (int kk = 0; kk < 16; ++kk) {
        int n = n0 + kk * 32 + lq * 8;
        bf16x8 a[2], bb[2];
#pragma unroll
        for (int mt = 0; mt < 2; ++mt) {
            bf16x8 raw = *(const bf16x8*)(kb + (size_t)(mt * 16 + lr) * NPOS + n);
            bf16x8 e;
#pragma unroll
            for (int j = 0; j < 8; ++j)
                e[j] = (short)f2b(__expf(b2f((ushort_t)raw[j]) - km[mt]));
            a[mt] = e;
        }
#pragma unroll
        for (int nt = 0; nt < 2; ++nt)
            bb[nt] = *(const bf16x8*)(vb + (size_t)(nt * 16 + lr) * NPOS + n);
#pragma unroll
        for (int mt = 0; mt < 2; ++mt)
#pragma unroll
            for (int nt = 0; nt < 2; ++nt)
                acc[mt][nt] = __builtin_amdgcn_mfma_f32_16x16x32_bf16(a[mt], bb[nt], acc[mt][nt], 0, 0, 0);
    }

#pragma unroll
    for (int mt = 0; mt < 2; ++mt)
#pragma unroll
        for (int nt = 0; nt < 2; ++nt)
#pragma unroll
            for (int r = 0; r < 4; ++r)
                atomicAdd(&ctx[((size_t)bh * 32 + mt * 16 + lq * 4 + r) * 32 + nt * 16 + lr],
                          acc[mt][nt][r]);
}

// ---------------- Kernel 4: q-softmax * scale * kinv, attn = ctx^T @ q (in-place over q slot) ----------------
__global__ __launch_bounds__(256) void k_attn(ushort_t* __restrict__ qkv,
                                              const float* __restrict__ ctx,
                                              const float* __restrict__ kinv) {
    int b = blockIdx.y;
    int t = threadIdx.x;
    int p = blockIdx.x * 256 + t;
    __shared__ float cs[4096];
    __shared__ float kv[128];
#pragma unroll
    for (int i = 0; i < 16; ++i) cs[t + i * 256] = ctx[(size_t)b * 4096 + t + i * 256];
    if (t < 128) kv[t] = kinv[b * 128 + t];
    __syncthreads();

    ushort_t* qb = qkv + (size_t)b * O3 * NPOS + p;
    const float scale = 0.17677669529663687f;  // 32^-0.5

    for (int h = 0; h < 4; ++h) {
        float q[32];
#pragma unroll
        for (int d = 0; d < 32; ++d) q[d] = b2f(qb[(size_t)(h * 32 + d) * NPOS]);
        float m = q[0];
#pragma unroll
        for (int d = 1; d < 32; ++d) m = fmaxf(m, q[d]);
        float s = 0.f;
#pragma unroll
        for (int d = 0; d < 32; ++d) { q[d] = __expf(q[d] - m); s += q[d]; }
        float inv = scale / s;
#pragma unroll
        for (int d = 0; d < 32; ++d) q[d] *= inv * kv[h * 32 + d];

        float o[32];
#pragma unroll
        for (int e = 0; e < 32; ++e) o[e] = 0.f;
        const float* ch = cs + h * 1024;
        for (int d = 0; d < 32; ++d) {
            float qv = q[d];
#pragma unroll
            for (int e = 0; e < 32; ++e) o[e] = fmaf(ch[d * 32 + e], qv, o[e]);
        }
#pragma unroll
        for (int e = 0; e < 32; ++e) qb[(size_t)(h * 32 + e) * NPOS] = f2b(o[e]);
    }
}

// ---------------- Kernel 5: y = w_out(128x128) @ attn + b_out, then LayerNorm over C ----------------
__global__ __launch_bounds__(256) void k_out(const ushort_t* __restrict__ qkv,
                                             const ushort_t* __restrict__ wout,
                                             const float* __restrict__ bout,
                                             const float* __restrict__ lng,
                                             const float* __restrict__ lnb,
                                             float* __restrict__ out) {
    __shared__ ushort_t at[32][136];
    __shared__ float redS[4][32], redQ[4][32];
    int t = threadIdx.x, b = blockIdx.y, p0 = blockIdx.x * 32;
    stage_tile_bf(qkv + (size_t)b * O3 * NPOS + p0, t, at);   // attn lives in the q slot (rows 0..127)
    __syncthreads();

    int w = t >> 6, l = t & 63, lr = l & 15, lq = l >> 4;
    f32x4 acc[2][2];
#pragma unroll
    for (int mt = 0; mt < 2; ++mt)
#pragma unroll
        for (int nt = 0; nt < 2; ++nt) acc[mt][nt] = (f32x4){0.f, 0.f, 0.f, 0.f};

#pragma unroll
    for (int kk = 0; kk < 4; ++kk) {
        bf16x8 a[2], bb[2];
#pragma unroll
        for (int mt = 0; mt < 2; ++mt)
            a[mt] = *(const bf16x8*)(wout + (size_t)(w * 32 + mt * 16 + lr) * HID + kk * 32 + lq * 8);
#pragma unroll
        for (int nt = 0; nt < 2; ++nt)
            bb[nt] = *(const bf16x8*)(&at[nt * 16 + lr][kk * 32 + lq * 8]);
#pragma unroll
        for (int mt = 0; mt < 2; ++mt)
#pragma unroll
            for (int nt = 0; nt < 2; ++nt)
                acc[mt][nt] = __builtin_amdgcn_mfma_f32_16x16x32_bf16(a[mt], bb[nt], acc[mt][nt], 0, 0, 0);
    }

    // bias + per-column LN stats (this wave's 32 rows)
    float vals[2][2][4];
    float colS[2] = {0.f, 0.f}, colQ[2] = {0.f, 0.f};
#pragma unroll
    for (int mt = 0; mt < 2; ++mt) {
#pragma unroll
        for (int r = 0; r < 4; ++r) {
            int c = w * 32 + mt * 16 + lq * 4 + r;
            float bias = bout[c];
#pragma unroll
            for (int nt = 0; nt < 2; ++nt) {
                float v = acc[mt][nt][r] + bias;
                vals[mt][nt][r] = v;
                colS[nt] += v;
                colQ[nt] += v * v;
            }
        }
    }
#pragma unroll
    for (int nt = 0; nt < 2; ++nt) {
        colS[nt] += __shfl_xor(colS[nt], 16); colQ[nt] += __shfl_xor(colQ[nt], 16);
        colS[nt] += __shfl_xor(colS[nt], 32); colQ[nt] += __shfl_xor(colQ[nt], 32);
        if (lq == 0) { redS[w][nt * 16 + lr] = colS[nt]; redQ[w][nt * 16 + lr] = colQ[nt]; }
    }
    __syncthreads();

    float mean[2], rstd[2];
#pragma unroll
    for (int nt = 0; nt < 2; ++nt) {
        int col = nt * 16 + lr;
        float S = redS[0][col] + redS[1][col] + redS[2][col] + redS[3][col];
        float Q = redQ[0][col] + redQ[1][col] + redQ[2][col] + redQ[3][col];
        float mu = S * (1.f / 128.f);
        float var = Q * (1.f / 128.f) - mu * mu;
        mean[nt] = mu;
        rstd[nt] = rsqrtf(var + 1e-5f);
    }

#pragma unroll
    for (int mt = 0; mt < 2; ++mt)
#pragma unroll
        for (int r = 0; r < 4; ++r) {
            int c = w * 32 + mt * 16 + lq * 4 + r;
            float g = lng[c], lb = lnb[c];
#pragma unroll
            for (int nt = 0; nt < 2; ++nt)
                out[((size_t)b * HID + c) * NPOS + p0 + nt * 16 + lr] =
                    (vals[mt][nt][r] - mean[nt]) * rstd[nt] * g + lb;
        }
}

extern "C" void kernel_launch(void* const* d_in, const int* in_sizes, int n_in,
                              void* d_out, int out_size, void* d_ws, size_t ws_size,
                              hipStream_t stream) {
    const float* x    = (const float*)d_in[0];
    const float* wqkv = (const float*)d_in[1];
    const float* wout = (const float*)d_in[2];
    const float* bout = (const float*)d_in[3];
    const float* lng  = (const float*)d_in[4];
    const float* lnb  = (const float*)d_in[5];
    float* out = (float*)d_out;

    char* ws = (char*)d_ws;
    ushort_t* qkv     = (ushort_t*)ws;                       // 16*384*16384*2 = 201,326,592 B
    ushort_t* wq_bf   = (ushort_t*)(ws + 201326592ull);      // 49152 ushort
    ushort_t* wout_bf = (ushort_t*)(ws + 201424896ull);      // 16384 ushort
    float*    kmax    = (float*)   (ws + 201457664ull);      // 2048 f32
    float*    kinv    = (float*)   (ws + 201465856ull);      // 2048 f32
    float*    ctx     = (float*)   (ws + 201474048ull);      // 64*32*32 f32 = 262,144 B

    hipMemsetAsync(ctx, 0, 64 * 32 * 32 * sizeof(float), stream);

    k_cvt<<<dim3(256), dim3(256), 0, stream>>>(wqkv, wout, wq_bf, wout_bf);

    dim3 blk(256);
    dim3 g1(NPOS / 32, 16);
    k_qkv<<<g1, blk, 0, stream>>>(x, wq_bf, qkv);

    k_stats<<<dim3(2048), blk, 0, stream>>>(qkv, kmax, kinv);

    dim3 g3(NPOS / 512, 64);
    k_ctx<<<g3, dim3(64), 0, stream>>>(qkv, kmax, ctx);

    dim3 g4(NPOS / 256, 16);
    k_attn<<<g4, blk, 0, stream>>>(qkv, ctx, kinv);

    dim3 g5(NPOS / 32, 16);
    k_out<<<g5, blk, 0, stream>>>(qkv, wout_bf, bout, lng, lnb, out);
}

// Round 3
// 383.135 us; speedup vs baseline: 1.4914x; 1.4914x over previous
//
#include <hip/hip_runtime.h>

typedef unsigned short ushort_t;
typedef __attribute__((ext_vector_type(8))) short bf16x8;
typedef __attribute__((ext_vector_type(4))) float f32x4;

#define NPOS 16384   // H*W
#define CIN 128
#define O3  384
#define HID 128

__device__ inline float b2f(ushort_t u) {
    union { unsigned int i; float f; } z; z.i = ((unsigned int)u) << 16; return z.f;
}
__device__ inline ushort_t f2b(float f) {
    union { float f; unsigned int u; } x; x.f = f;
    unsigned int lsb = (x.u >> 16) & 1u;
    unsigned int r = x.u + 0x7fffu + lsb;
    return (ushort_t)(r >> 16);
}

// ---------------- Kernel 0: one-time fp32 -> bf16 conversion of w_qkv ----------------
__global__ __launch_bounds__(256) void k_cvt(const float* __restrict__ wq,
                                             ushort_t* __restrict__ wq_bf) {
    int i = blockIdx.x * 256 + threadIdx.x;   // 0 .. 49151
    wq_bf[i] = f2b(wq[i]);
}

// Stage a (128 ch x 64 pos) fp32 tile -> bf16 LDS [pos][ch(136)]
__device__ inline void stage_x64(const float* __restrict__ x, int t, ushort_t (*xt)[136]) {
    int q4 = t & 15;          // position quad 0..15
    int ch0 = t >> 4;         // 0..15
    const float* xp = x + q4 * 4;
#pragma unroll
    for (int it = 0; it < 8; ++it) {
        int c = it * 16 + ch0;
        float4 v = *(const float4*)(xp + (size_t)c * NPOS);
        xt[q4 * 4 + 0][c] = f2b(v.x);
        xt[q4 * 4 + 1][c] = f2b(v.y);
        xt[q4 * 4 + 2][c] = f2b(v.z);
        xt[q4 * 4 + 3][c] = f2b(v.w);
    }
}

// ---------------- Kernel A: fused k/v GEMM + exp + ctx_raw & kexp accumulation ----------------
// ctx_raw[bh][d][e] = sum_n exp(k[d,n]) * v[e,n];  kexp[bh][d] = sum_n exp(k[d,n])
// k,v never touch HBM. Wave w handles head w (k rows 128+w*32, v rows 256+w*32).
__global__ __launch_bounds__(256) void k_ctxsum(const float* __restrict__ x,
                                                const ushort_t* __restrict__ wq,
                                                float* __restrict__ kexp,
                                                float* __restrict__ ctx) {
    __shared__ ushort_t xt[64][136];
    __shared__ ushort_t kb[4][32][40];   // per-wave exp(k) transpose: [d][pos], 80B rows
    __shared__ ushort_t vb[4][32][40];   // per-wave v transpose
    int t = threadIdx.x, b = blockIdx.y, p0 = blockIdx.x * 64;
    stage_x64(x + (size_t)b * CIN * NPOS + p0, t, xt);

    int w = t >> 6, l = t & 63, lr = l & 15, lq = l >> 4;

    // hoist weight fragments (reused for both chunks)
    bf16x8 ka[2][4], va[2][4];
#pragma unroll
    for (int g = 0; g < 2; ++g)
#pragma unroll
        for (int kk = 0; kk < 4; ++kk) {
            ka[g][kk] = *(const bf16x8*)(wq + (size_t)(128 + w * 32 + g * 16 + lr) * CIN + kk * 32 + lq * 8);
            va[g][kk] = *(const bf16x8*)(wq + (size_t)(256 + w * 32 + g * 16 + lr) * CIN + kk * 32 + lq * 8);
        }
    __syncthreads();

    f32x4 cacc[2][2];
#pragma unroll
    for (int mt = 0; mt < 2; ++mt)
#pragma unroll
        for (int nt = 0; nt < 2; ++nt) cacc[mt][nt] = (f32x4){0.f, 0.f, 0.f, 0.f};
    float sacc[2][4];
#pragma unroll
    for (int g = 0; g < 2; ++g)
#pragma unroll
        for (int r = 0; r < 4; ++r) sacc[g][r] = 0.f;

#pragma unroll
    for (int c4 = 0; c4 < 2; ++c4) {
        bf16x8 xb[2][4];
#pragma unroll
        for (int nt = 0; nt < 2; ++nt)
#pragma unroll
            for (int kk = 0; kk < 4; ++kk)
                xb[nt][kk] = *(const bf16x8*)(&xt[c4 * 32 + nt * 16 + lr][kk * 32 + lq * 8]);

        f32x4 kacc[2][2], vacc[2][2];
#pragma unroll
        for (int g = 0; g < 2; ++g)
#pragma unroll
            for (int nt = 0; nt < 2; ++nt) {
                kacc[g][nt] = (f32x4){0.f, 0.f, 0.f, 0.f};
                vacc[g][nt] = (f32x4){0.f, 0.f, 0.f, 0.f};
            }
#pragma unroll
        for (int g = 0; g < 2; ++g)
#pragma unroll
            for (int nt = 0; nt < 2; ++nt)
#pragma unroll
                for (int kk = 0; kk < 4; ++kk) {
                    kacc[g][nt] = __builtin_amdgcn_mfma_f32_16x16x32_bf16(ka[g][kk], xb[nt][kk], kacc[g][nt], 0, 0, 0);
                    vacc[g][nt] = __builtin_amdgcn_mfma_f32_16x16x32_bf16(va[g][kk], xb[nt][kk], vacc[g][nt], 0, 0, 0);
                }

        // exp(k) + transpose both into per-wave LDS ([ch][pos] for A/B fragments)
#pragma unroll
        for (int g = 0; g < 2; ++g)
#pragma unroll
            for (int nt = 0; nt < 2; ++nt)
#pragma unroll
                for (int r = 0; r < 4; ++r) {
                    float e = __expf(kacc[g][nt][r]);
                    sacc[g][r] += e;
                    kb[w][g * 16 + lq * 4 + r][nt * 16 + lr] = f2b(e);
                    vb[w][g * 16 + lq * 4 + r][nt * 16 + lr] = f2b(vacc[g][nt][r]);
                }
        __syncthreads();

        bf16x8 ak[2], av[2];
#pragma unroll
        for (int mt = 0; mt < 2; ++mt) ak[mt] = *(const bf16x8*)(&kb[w][mt * 16 + lr][lq * 8]);
#pragma unroll
        for (int nt = 0; nt < 2; ++nt) av[nt] = *(const bf16x8*)(&vb[w][nt * 16 + lr][lq * 8]);
#pragma unroll
        for (int mt = 0; mt < 2; ++mt)
#pragma unroll
            for (int nt = 0; nt < 2; ++nt)
                cacc[mt][nt] = __builtin_amdgcn_mfma_f32_16x16x32_bf16(ak[mt], av[nt], cacc[mt][nt], 0, 0, 0);
        __syncthreads();
    }

    // accumulate ctx_raw (fp32 atomics; C layout: row=d, col=e)
#pragma unroll
    for (int mt = 0; mt < 2; ++mt)
#pragma unroll
        for (int nt = 0; nt < 2; ++nt)
#pragma unroll
            for (int r = 0; r < 4; ++r)
                atomicAdd(&ctx[((size_t)(b * 4 + w) * 32 + mt * 16 + lq * 4 + r) * 32 + nt * 16 + lr],
                          cacc[mt][nt][r]);

    // sum over positions (lr lanes) then accumulate kexp
#pragma unroll
    for (int g = 0; g < 2; ++g)
#pragma unroll
        for (int r = 0; r < 4; ++r) {
            float s = sacc[g][r];
            s += __shfl_xor(s, 1); s += __shfl_xor(s, 2);
            s += __shfl_xor(s, 4); s += __shfl_xor(s, 8);
            if (lr == 0)
                atomicAdd(&kexp[(b * 4 + w) * 32 + g * 16 + lq * 4 + r], s);
        }
}

// ---------------- Kernel B: Weff[b][c][h*32+d] = (1/kexp[bhd]) * sum_e wo[c][h*32+e]*ctx[bh][d][e] ----------------
__global__ __launch_bounds__(256) void k_weff(const float* __restrict__ wo,
                                              const float* __restrict__ ctx,
                                              const float* __restrict__ kexp,
                                              ushort_t* __restrict__ weff) {
    int bh = blockIdx.x, b = bh >> 2, h = bh & 3;
    __shared__ float wos[128][32];
    __shared__ float cs[32][33];
    int t = threadIdx.x;
#pragma unroll
    for (int k = 0; k < 16; ++k) {
        int idx = k * 256 + t; int c = idx >> 5, e = idx & 31;
        wos[c][e] = wo[(size_t)c * HID + h * 32 + e];
    }
#pragma unroll
    for (int k = 0; k < 4; ++k) {
        int idx = k * 256 + t; int d = idx >> 5, e = idx & 31;
        cs[d][e] = ctx[((size_t)bh * 32 + d) * 32 + e];
    }
    __syncthreads();
#pragma unroll
    for (int k = 0; k < 16; ++k) {
        int idx = k * 256 + t; int c = idx >> 5, d = idx & 31;
        float s = 0.f;
#pragma unroll
        for (int e = 0; e < 32; ++e) s += wos[c][e] * cs[d][e];
        float kin = 1.0f / kexp[bh * 32 + d];
        weff[((size_t)b * HID + c) * HID + h * 32 + d] = f2b(s * kin);
    }
}

// ---------------- Kernel C: q GEMM -> q softmax -> out = Weff @ q~ + bias -> LayerNorm ----------------
__global__ __launch_bounds__(256) void k_outf(const float* __restrict__ x,
                                              const ushort_t* __restrict__ wq,
                                              const ushort_t* __restrict__ weff,
                                              const float* __restrict__ bout,
                                              const float* __restrict__ lng,
                                              const float* __restrict__ lnb,
                                              float* __restrict__ out) {
    __shared__ ushort_t buf[64][136];     // x tile, then reused for q~ tile
    __shared__ float redS[4][64], redQ[4][64];
    int t = threadIdx.x, b = blockIdx.y, p0 = blockIdx.x * 64;
    stage_x64(x + (size_t)b * CIN * NPOS + p0, t, buf);

    int w = t >> 6, l = t & 63, lr = l & 15, lq = l >> 4;

    bf16x8 qa[2][4];
#pragma unroll
    for (int g = 0; g < 2; ++g)
#pragma unroll
        for (int kk = 0; kk < 4; ++kk)
            qa[g][kk] = *(const bf16x8*)(wq + (size_t)(w * 32 + g * 16 + lr) * CIN + kk * 32 + lq * 8);
    __syncthreads();

    // q = Wq(head w) @ x for all 4 position sub-tiles
    f32x4 qacc[2][4];
#pragma unroll
    for (int g = 0; g < 2; ++g)
#pragma unroll
        for (int j = 0; j < 4; ++j) qacc[g][j] = (f32x4){0.f, 0.f, 0.f, 0.f};
#pragma unroll
    for (int j = 0; j < 4; ++j) {
        bf16x8 xb[4];
#pragma unroll
        for (int kk = 0; kk < 4; ++kk)
            xb[kk] = *(const bf16x8*)(&buf[j * 16 + lr][kk * 32 + lq * 8]);
#pragma unroll
        for (int g = 0; g < 2; ++g)
#pragma unroll
            for (int kk = 0; kk < 4; ++kk)
                qacc[g][j] = __builtin_amdgcn_mfma_f32_16x16x32_bf16(qa[g][kk], xb[kk], qacc[g][j], 0, 0, 0);
    }
    __syncthreads();   // all x reads complete before overwriting buf

    // softmax over d (32 channels of head w) per position; write q~ into buf[pos][ch]
    const float scale = 0.17677669529663687f;  // 32^-0.5
#pragma unroll
    for (int j = 0; j < 4; ++j) {
        float m = -1e30f;
#pragma unroll
        for (int g = 0; g < 2; ++g)
#pragma unroll
            for (int r = 0; r < 4; ++r) m = fmaxf(m, qacc[g][j][r]);
        m = fmaxf(m, __shfl_xor(m, 16));
        m = fmaxf(m, __shfl_xor(m, 32));
        float e[2][4], s = 0.f;
#pragma unroll
        for (int g = 0; g < 2; ++g)
#pragma unroll
            for (int r = 0; r < 4; ++r) { e[g][r] = __expf(qacc[g][j][r] - m); s += e[g][r]; }
        s += __shfl_xor(s, 16);
        s += __shfl_xor(s, 32);
        float inv = scale / s;
#pragma unroll
        for (int g = 0; g < 2; ++g) {
            ushort4 u;
            u.x = f2b(e[g][0] * inv); u.y = f2b(e[g][1] * inv);
            u.z = f2b(e[g][2] * inv); u.w = f2b(e[g][3] * inv);
            *(ushort4*)(&buf[j * 16 + lr][w * 32 + g * 16 + lq * 4]) = u;
        }
    }
    __syncthreads();

    // out = Weff[b] @ q~  (K=128 over hd channels)
    bf16x8 wa[2][4];
#pragma unroll
    for (int g = 0; g < 2; ++g)
#pragma unroll
        for (int kk = 0; kk < 4; ++kk)
            wa[g][kk] = *(const bf16x8*)(weff + ((size_t)b * HID + w * 32 + g * 16 + lr) * HID + kk * 32 + lq * 8);
    f32x4 oacc[2][4];
#pragma unroll
    for (int g = 0; g < 2; ++g)
#pragma unroll
        for (int j = 0; j < 4; ++j) oacc[g][j] = (f32x4){0.f, 0.f, 0.f, 0.f};
#pragma unroll
    for (int j = 0; j < 4; ++j) {
        bf16x8 sb[4];
#pragma unroll
        for (int kk = 0; kk < 4; ++kk)
            sb[kk] = *(const bf16x8*)(&buf[j * 16 + lr][kk * 32 + lq * 8]);
#pragma unroll
        for (int g = 0; g < 2; ++g)
#pragma unroll
            for (int kk = 0; kk < 4; ++kk)
                oacc[g][j] = __builtin_amdgcn_mfma_f32_16x16x32_bf16(wa[g][kk], sb[kk], oacc[g][j], 0, 0, 0);
    }

    // bias + LayerNorm over 128 channels per position
    float vals[2][4][4];
    float colS[4] = {0.f, 0.f, 0.f, 0.f}, colQ[4] = {0.f, 0.f, 0.f, 0.f};
#pragma unroll
    for (int g = 0; g < 2; ++g)
#pragma unroll
        for (int r = 0; r < 4; ++r) {
            int c = w * 32 + g * 16 + lq * 4 + r;
            float bias = bout[c];
#pragma unroll
            for (int j = 0; j < 4; ++j) {
                float v = oacc[g][j][r] + bias;
                vals[g][j][r] = v;
                colS[j] += v;
                colQ[j] += v * v;
            }
        }
#pragma unroll
    for (int j = 0; j < 4; ++j) {
        colS[j] += __shfl_xor(colS[j], 16); colQ[j] += __shfl_xor(colQ[j], 16);
        colS[j] += __shfl_xor(colS[j], 32); colQ[j] += __shfl_xor(colQ[j], 32);
        if (lq == 0) { redS[w][j * 16 + lr] = colS[j]; redQ[w][j * 16 + lr] = colQ[j]; }
    }
    __syncthreads();

    float mean[4], rstd[4];
#pragma unroll
    for (int j = 0; j < 4; ++j) {
        int col = j * 16 + lr;
        float S = redS[0][col] + redS[1][col] + redS[2][col] + redS[3][col];
        float Q = redQ[0][col] + redQ[1][col] + redQ[2][col] + redQ[3][col];
        float mu = S * (1.f / 128.f);
        float var = Q * (1.f / 128.f) - mu * mu;
        mean[j] = mu;
        rstd[j] = rsqrtf(var + 1e-5f);
    }

#pragma unroll
    for (int g = 0; g < 2; ++g)
#pragma unroll
        for (int r = 0; r < 4; ++r) {
            int c = w * 32 + g * 16 + lq * 4 + r;
            float gg = lng[c], lb = lnb[c];
#pragma unroll
            for (int j = 0; j < 4; ++j)
                out[((size_t)b * HID + c) * NPOS + p0 + j * 16 + lr] =
                    (vals[g][j][r] - mean[j]) * rstd[j] * gg + lb;
        }
}

extern "C" void kernel_launch(void* const* d_in, const int* in_sizes, int n_in,
                              void* d_out, int out_size, void* d_ws, size_t ws_size,
                              hipStream_t stream) {
    const float* x    = (const float*)d_in[0];
    const float* wqkv = (const float*)d_in[1];
    const float* wout = (const float*)d_in[2];
    const float* bout = (const float*)d_in[3];
    const float* lng  = (const float*)d_in[4];
    const float* lnb  = (const float*)d_in[5];
    float* out = (float*)d_out;

    char* ws = (char*)d_ws;
    float*    kexp  = (float*)ws;                      // 2048 f32        @ 0
    float*    ctx   = (float*)(ws + 8192);             // 65536 f32       @ 8192
    ushort_t* wq_bf = (ushort_t*)(ws + 270336);        // 49152 bf16      @ 270336
    ushort_t* weff  = (ushort_t*)(ws + 368640);        // 16*128*128 bf16 @ 368640

    hipMemsetAsync(ws, 0, 270336, stream);             // kexp + ctx

    k_cvt<<<dim3(192), dim3(256), 0, stream>>>(wqkv, wq_bf);

    dim3 gA(NPOS / 64, 16);
    k_ctxsum<<<gA, dim3(256), 0, stream>>>(x, wq_bf, kexp, ctx);

    k_weff<<<dim3(64), dim3(256), 0, stream>>>(wout, ctx, kexp, weff);

    dim3 gC(NPOS / 64, 16);
    k_outf<<<gC, dim3(256), 0, stream>>>(x, wq_bf, weff, bout, lng, lnb, out);
}